// Round 8
// baseline (189.882 us; speedup 1.0000x reference)
//
#include <hip/hip_runtime.h>
#include <hip/hip_bf16.h>
#include <stdint.h>

// Problem constants
#define DM    2048
#define NH    16
#define NKVH  4
#define HD    128
#define WIN   512
#define SEQL  2048
#define BAT   2
#define MR    (BAT*SEQL)        // 4096 rows
#define NQKV  3072              // 2048 q + 512 k + 512 v
#define QKSCALE 0.08838834764831845f
#define CAP   50.0f
// C1: folded into Q at RoPE. sv = y * 2*log2e/CAP where y = q.k*QKSCALE
#define C1F (QKSCALE * 2.0f * 1.4426950408889634f / CAP)
#define C2F (-144.26950408889634f)   // -2*CAP*log2e ; p' = 2^(C2F/(2^sv+1))

typedef unsigned short u16;
typedef __attribute__((ext_vector_type(8))) short short8;
typedef __attribute__((ext_vector_type(4))) float f32x4;
typedef __attribute__((ext_vector_type(16))) float f32x16;

__device__ __forceinline__ u16 f2bf(float f) {
  union { float f; uint32_t u; } v; v.f = f;
  uint32_t r = v.u + 0x7FFFu + ((v.u >> 16) & 1u);
  return (u16)(r >> 16);
}
__device__ __forceinline__ float bf2f(u16 h) {
  union { uint32_t u; float f; } v; v.u = ((uint32_t)h) << 16; return v.f;
}
__device__ __forceinline__ void gld16(const void* g, void* l) {
  __builtin_amdgcn_global_load_lds((const __attribute__((address_space(1))) void*)g,
                                   (__attribute__((address_space(3))) void*)l,
                                   16, 0, 0);
}
// p' = exp(CAP*tanh(y/CAP)) / e^CAP = 2^( C2F / (2^sv + 1) ), sv pre-scaled via C1F.
// Real intrinsics (not inline asm) so TRANS hazard wait-states are inserted (R6 fix).
__device__ __forceinline__ float exp_softcap(float sv) {
  float t = __builtin_amdgcn_exp2f(sv);
  float u = __builtin_amdgcn_rcpf(t + 1.0f);
  return __builtin_amdgcn_exp2f(u * C2F);
}

// ---------------- elementwise: fp32 -> bf16 cast ----------------
__global__ void k_cast(const float* __restrict__ src, u16* __restrict__ dst, int n4) {
  int i = blockIdx.x * 256 + threadIdx.x;
  if (i >= n4) return;
  float4 v = ((const float4*)src)[i];
  ushort4 o;
  o.x = f2bf(v.x); o.y = f2bf(v.y); o.z = f2bf(v.z); o.w = f2bf(v.w);
  ((ushort4*)dst)[i] = o;
}

// ---------------- RoPE cos/sin table: [S][64] ----------------
__global__ void k_rope_table(float* __restrict__ c, float* __restrict__ sn) {
  int s = blockIdx.x, i = threadIdx.x;
  float invf = expf(-(float)i * (9.210340371976184f / 64.0f));
  float a = (float)s * invf;
  c[(s << 6) + i]  = cosf(a);
  sn[(s << 6) + i] = sinf(a);
}

// ---------------- GEMM: C[M][N] = A[M][K] * B[N][K]^T (unchanged, ~880-940 TF) ----------------
template <typename OutT>
__global__ __launch_bounds__(256, 3) void k_gemm_bt(const u16* __restrict__ A,
                                                    const u16* __restrict__ Bm,
                                                    OutT* __restrict__ C,
                                                    int N, int K) {
  __shared__ __align__(16) u16 ldsA[128 * 64];
  __shared__ __align__(16) u16 ldsB[128 * 64];
  const int t = threadIdx.x;

  const int nwg  = gridDim.x * gridDim.y;
  const int flat = blockIdx.y * gridDim.x + blockIdx.x;
  const int cpx  = nwg >> 3;
  const int swz  = (flat & 7) * cpx + (flat >> 3);
  const int bn = swz % gridDim.x, bm = swz / gridDim.x;

  const int m0 = bm * 128, n0 = bn * 128;
  const int lane = t & 63, wid = t >> 6;
  const int lr = lane & 15, lk = lane >> 4;
  const int wr = (wid >> 1) * 64, wc = (wid & 1) * 64;
  const int nt = K >> 6;

  const int srow = t >> 3;
  const int scol = (((t & 7) ^ (srow & 7)) << 3);

  f32x4 acc[4][4];
  #pragma unroll
  for (int mi = 0; mi < 4; ++mi)
    #pragma unroll
    for (int ni = 0; ni < 4; ++ni) acc[mi][ni] = f32x4{0.f, 0.f, 0.f, 0.f};

  for (int kt = 0; kt < nt; ++kt) {
    {
      const u16* a0 = A  + (size_t)(m0 + srow) * K + kt * 64 + scol;
      const u16* b0 = Bm + (size_t)(n0 + srow) * K + kt * 64 + scol;
      #pragma unroll
      for (int i = 0; i < 4; ++i) {
        gld16(a0 + (size_t)(i * 32) * K, &ldsA[i * 2048 + t * 8]);
        gld16(b0 + (size_t)(i * 32) * K, &ldsB[i * 2048 + t * 8]);
      }
    }
    __syncthreads();
    #pragma unroll
    for (int ks = 0; ks < 2; ++ks) {
      const int c = ks * 4 + lk;
      short8 af[4], bfv[4];
      #pragma unroll
      for (int mi = 0; mi < 4; ++mi) {
        const int ra = wr + mi * 16 + lr;
        af[mi] = *(const short8*)(ldsA + ra * 64 + ((c ^ (ra & 7)) << 3));
      }
      #pragma unroll
      for (int ni = 0; ni < 4; ++ni) {
        const int rb = wc + ni * 16 + lr;
        bfv[ni] = *(const short8*)(ldsB + rb * 64 + ((c ^ (rb & 7)) << 3));
      }
      #pragma unroll
      for (int mi = 0; mi < 4; ++mi)
        #pragma unroll
        for (int ni = 0; ni < 4; ++ni)
          acc[mi][ni] = __builtin_amdgcn_mfma_f32_16x16x32_bf16(af[mi], bfv[ni], acc[mi][ni], 0, 0, 0);
    }
    if (kt + 1 < nt) __syncthreads();
  }

  #pragma unroll
  for (int mi = 0; mi < 4; ++mi) {
    #pragma unroll
    for (int ni = 0; ni < 4; ++ni) {
      const int r0 = m0 + wr + mi * 16 + lk * 4;
      const int c  = n0 + wc + ni * 16 + lr;
      #pragma unroll
      for (int r = 0; r < 4; ++r) {
        float v = acc[mi][ni][r];
        if constexpr (__is_same(OutT, float)) C[(size_t)(r0 + r) * N + c] = v;
        else                                  C[(size_t)(r0 + r) * N + c] = f2bf(v);
      }
    }
  }
}

// ---------------- RoPE on Q (pre-scaled by C1F for the attn softcap-exp) ----------------
__global__ void k_rope_q(const u16* __restrict__ C, const float* __restrict__ cosT,
                         const float* __restrict__ sinT, u16* __restrict__ qr) {
  int idx = blockIdx.x * 256 + threadIdx.x;
  int i = idx & 63, hh = (idx >> 6) & 15, m = idx >> 10;
  int s = m & (SEQL - 1), b = m >> 11;
  size_t cb = (size_t)m * NQKV + hh * HD + i;
  float x1 = bf2f(C[cb]), x2 = bf2f(C[cb + 64]);
  float c = cosT[(s << 6) + i], sn = sinT[(s << 6) + i];
  size_t ob = ((size_t)(b * NH + hh) * SEQL + s) * HD + i;
  qr[ob]      = f2bf((x1 * c - x2 * sn) * C1F);
  qr[ob + 64] = f2bf((x2 * c + x1 * sn) * C1F);
}

// ---------------- RoPE on K ----------------
__global__ void k_rope_k(const u16* __restrict__ C, const float* __restrict__ cosT,
                         const float* __restrict__ sinT, u16* __restrict__ kr) {
  int idx = blockIdx.x * 256 + threadIdx.x;
  int i = idx & 63, kvh = (idx >> 6) & 3, m = idx >> 8;
  int s = m & (SEQL - 1), b = m >> 11;
  size_t cb = (size_t)m * NQKV + 2048 + kvh * HD + i;
  float x1 = bf2f(C[cb]), x2 = bf2f(C[cb + 64]);
  float c = cosT[(s << 6) + i], sn = sinT[(s << 6) + i];
  size_t ob = ((size_t)(b * NKVH + kvh) * SEQL + s) * HD + i;
  kr[ob]      = f2bf(x1 * c - x2 * sn);
  kr[ob + 64] = f2bf(x2 * c + x1 * sn);
}

// ---------------- V transpose: -> vt[b][kvh][d][s] ----------------
__global__ void k_vt(const u16* __restrict__ C, u16* __restrict__ vt) {
  int idx = blockIdx.x * 256 + threadIdx.x;
  int s = idx & (SEQL - 1);
  int d = (idx >> 11) & 127;
  int kvh = (idx >> 18) & 3;
  int b = idx >> 20;
  int m = b * SEQL + s;
  vt[idx] = C[(size_t)m * NQKV + 2560 + kvh * HD + d];
}

// ---------------- flash attention: window=512, softcap, GQA ----------------
// 32x32x16 MFMA structure (m214-ladder): 4 waves x 32 q-rows = 128 q/block.
// Per 32-kv tile per wave: QK^T = 8 MFMA + 8 ds_read_b128, PV = 8 MFMA + 8
// ds_read_b128 (was 48 MFMA + 50 reads per 32q at 16x16 -> 3x fewer LDS reads).
// Swapped QK^T: S^T=mfma(K,Q); lane owns q=q0w+(lane&31), 16 kv rows in regs.
// P->A-frag redistribution fully in-register: cvt_pk pairs + __shfl_xor(.,32)
// + selects (T12 mechanism) -- no P LDS bounce. No online softmax (softcap
// bounds scores; e^CAP cancels in O/l). K/V staging identical to R7.
__global__ __launch_bounds__(256, 2) void k_attn(const u16* __restrict__ qr,
                                                 const u16* __restrict__ kr,
                                                 const u16* __restrict__ vt,
                                                 u16* __restrict__ ao) {
  __shared__ __align__(16) u16 kbuf[2][32 * 128];   // [kv][d], byte bits[6:4]^=row&7
  __shared__ __align__(16) u16 vbuf[2][128 * 32];   // [d][kv], byte bits[5:4]^=(row>>1)&3

  const int t = threadIdx.x;
  const int wid = t >> 6, lane = t & 63;
  const int l31 = lane & 31, lh = lane >> 5;
  const int h = blockIdx.x, bq = blockIdx.y, b = blockIdx.z;
  const int kvh = h >> 2;
  const int Q0 = bq * 128;
  const int q0w = Q0 + wid * 32;
  const u16* qb = qr + (size_t)(b * NH + h) * SEQL * HD;
  const u16* kb = kr + (size_t)(b * NKVH + kvh) * SEQL * HD;
  const u16* vb = vt + (size_t)(b * NKVH + kvh) * HD * SEQL;

  // Q as B-frag for 32x32x16: lane holds Q[q0w+l31][ks*16 + lh*8 + j], j=0..7
  short8 qf[8];
  #pragma unroll
  for (int ks = 0; ks < 8; ++ks)
    qf[ks] = *(const short8*)(qb + (size_t)(q0w + l31) * HD + ks * 16 + lh * 8);

  f32x16 o[4];
  #pragma unroll
  for (int dt = 0; dt < 4; ++dt)
    #pragma unroll
    for (int i = 0; i < 16; ++i) o[dt][i] = 0.f;
  float lsum = 0.f;                       // per-lane partial for q = q0w + l31

  int lo = Q0 - (WIN - 1); if (lo < 0) lo = 0;
  const int ktlo = lo >> 5, kthi = (Q0 + 127) >> 5;

  auto stageK = [&](int bufi, int kv0) {
    #pragma unroll
    for (int i = 0; i < 2; ++i) {
      int c = t + i * 256;
      int bb = c << 4;
      int sb = bb ^ (((bb >> 8) & 7) << 4);   // involution on bits [6:4]
      gld16(kb + (size_t)(kv0 + (sb >> 8)) * HD + ((sb & 255) >> 1),
            &kbuf[bufi][c << 3]);
    }
  };
  auto stageV = [&](int bufi, int kv0) {
    #pragma unroll
    for (int i = 0; i < 2; ++i) {
      int c = t + i * 256;
      int bb = c << 4;
      int sb = bb ^ (((bb >> 7) & 3) << 4);   // involution on bits [5:4]
      gld16(vb + (size_t)(sb >> 6) * SEQL + kv0 + ((sb & 63) >> 1),
            &vbuf[bufi][c << 3]);
    }
  };

  stageK(0, ktlo << 5);
  stageV(0, ktlo << 5);
  __syncthreads();

  for (int kt = ktlo; kt <= kthi; ++kt) {
    const int cur = kt & 1;
    if (kt < kthi) { stageK(cur ^ 1, (kt + 1) << 5); stageV(cur ^ 1, (kt + 1) << 5); }
    const int kv0 = kt << 5;
    // wave-uniform skip: q rows q0w..q0w+31
    if (kv0 + 31 >= q0w - (WIN - 1) && kv0 <= q0w + 31) {
      // QK^T swapped: A = K (32kv x 16k slice), B = Q -> S^T[kv][q]
      f32x16 sv;
      #pragma unroll
      for (int i = 0; i < 16; ++i) sv[i] = 0.f;
      const u16* lks = kbuf[cur];
      #pragma unroll
      for (int ks = 0; ks < 8; ++ks) {
        int bo = (l31 * 256 + ks * 32 + lh * 16) ^ ((l31 & 7) << 4);
        short8 kf = *(const short8*)(lks + (bo >> 1));
        sv = __builtin_amdgcn_mfma_f32_32x32x16_bf16(kf, qf[ks], sv, 0, 0, 0);
      }
      // lane holds S^T[kv0 + (r&3)+8*(r>>2)+4*lh][q = q0w+l31], r = 0..15
      float p[16];
      const bool interior = (kv0 + 31 <= q0w) && (kv0 >= q0w + 32 - WIN);
      if (interior) {
        #pragma unroll
        for (int r = 0; r < 16; ++r) p[r] = exp_softcap(sv[r]);
      } else {
        const int qg = q0w + l31;
        #pragma unroll
        for (int r = 0; r < 16; ++r) {
          const int kg = kv0 + (r & 3) + 8 * (r >> 2) + 4 * lh;
          float e = exp_softcap(sv[r]);
          p[r] = (kg <= qg && kg > qg - WIN) ? e : 0.f;
        }
      }
      #pragma unroll
      for (int r = 0; r < 16; ++r) lsum += p[r];

      // pack p -> bf16 pairs; w[r2] covers kv pair per reg-pair (lane-local)
      uint32_t w[8];
      #pragma unroll
      for (int r2 = 0; r2 < 8; ++r2) {
        __hip_bfloat162 u = __float22bfloat162_rn(float2{p[2 * r2], p[2 * r2 + 1]});
        w[r2] = *(uint32_t*)&u;
      }
      // cross-half exchange (lane <-> lane+32): assemble PA frags in-register
      uint32_t z0 = lh ? w[0] : w[2], z1 = lh ? w[1] : w[3];
      uint32_t z2 = lh ? w[4] : w[6], z3 = lh ? w[5] : w[7];
      uint32_t x0 = __shfl_xor((int)z0, 32), x1 = __shfl_xor((int)z1, 32);
      uint32_t x2 = __shfl_xor((int)z2, 32), x3 = __shfl_xor((int)z3, 32);
      union U8 { uint32_t u[4]; short8 s; };
      U8 pa0, pa1;
      pa0.u[0] = lh ? x0 : w[0];  pa0.u[1] = lh ? x1 : w[1];
      pa0.u[2] = lh ? w[2] : x0;  pa0.u[3] = lh ? w[3] : x1;
      pa1.u[0] = lh ? x2 : w[4];  pa1.u[1] = lh ? x3 : w[5];
      pa1.u[2] = lh ? w[6] : x2;  pa1.u[3] = lh ? w[7] : x3;

      // PV: A = P (32q x 16kv), B = V^T rows -> O[q][d], 4 d-tiles of 32
      const u16* lvs = vbuf[cur];
      #pragma unroll
      for (int ks2 = 0; ks2 < 2; ++ks2) {
        const short8 paf = ks2 ? pa1.s : pa0.s;
        #pragma unroll
        for (int dt = 0; dt < 4; ++dt) {
          int row = dt * 32 + l31;
          int bo = (row * 64 + ks2 * 32 + lh * 16) ^ (((row >> 1) & 3) << 4);
          short8 vf = *(const short8*)(lvs + (bo >> 1));
          o[dt] = __builtin_amdgcn_mfma_f32_32x32x16_bf16(paf, vf, o[dt], 0, 0, 0);
        }
      }
    }
    __syncthreads();
  }

  // epilogue: lsum lives at q = q0w+l31 (both halves); O rows are crow-mapped
  lsum += __shfl_xor(lsum, 32);
  float linv = 1.0f / lsum;
  #pragma unroll
  for (int rr = 0; rr < 4; ++rr) {
    #pragma unroll
    for (int r = 0; r < 4; ++r) {
      const int crow = r + 8 * rr + 4 * lh;
      float inv = __shfl(linv, crow);
      const int srow = q0w + crow;
      u16* op = ao + (size_t)(b * SEQL + srow) * DM + h * HD;
      #pragma unroll
      for (int dt = 0; dt < 4; ++dt)
        op[dt * 32 + l31] = f2bf(o[dt][rr * 4 + r] * inv);
    }
  }
}

extern "C" void kernel_launch(void* const* d_in, const int* in_sizes, int n_in,
                              void* d_out, int out_size, void* d_ws, size_t ws_size,
                              hipStream_t stream) {
  (void)in_sizes; (void)n_in; (void)out_size; (void)ws_size;
  const float* hs = (const float*)d_in[0];
  const float* wq = (const float*)d_in[1];
  const float* wk = (const float*)d_in[2];
  const float* wv = (const float*)d_in[3];
  const float* wo = (const float*)d_in[4];
  float* out = (float*)d_out;

  u16* ws    = (u16*)d_ws;
  u16* A_bf  = ws;                      //  8,388,608  hs bf16 [4096][2048]
  u16* Wqkv  = A_bf + 8388608;          //  6,291,456  packed [3072][2048]
  u16* Cqkv  = Wqkv + 6291456;          // 12,582,912  [4096][3072]
  u16* q_r   = Cqkv + 12582912;         //  8,388,608  [b][h][s][128]
  u16* k_r   = q_r + 8388608;           //  2,097,152  [b][kvh][s][128]
  u16* vTb   = k_r + 2097152;           //  2,097,152  [b][kvh][128][s]
  float* cosT = (float*)(vTb + 2097152);
  float* sinT = cosT + 131072;
  u16* Wo   = Cqkv;                     // reuse Cqkv after rope/vt consume it
  u16* aout = A_bf;                     // reuse A_bf after QKV gemm

  k_cast<<<8192, 256, 0, stream>>>(hs, A_bf, 2097152);
  k_cast<<<4096, 256, 0, stream>>>(wq, Wqkv, 1048576);
  k_cast<<<1024, 256, 0, stream>>>(wk, Wqkv + 4194304, 262144);
  k_cast<<<1024, 256, 0, stream>>>(wv, Wqkv + 5242880, 262144);
  k_rope_table<<<2048, 64, 0, stream>>>(cosT, sinT);

  k_gemm_bt<u16><<<dim3(NQKV / 128, MR / 128), 256, 0, stream>>>(A_bf, Wqkv, Cqkv, NQKV, DM);

  k_rope_q<<<16384, 256, 0, stream>>>(Cqkv, cosT, sinT, q_r);
  k_rope_k<<<4096, 256, 0, stream>>>(Cqkv, cosT, sinT, k_r);
  k_vt<<<8192, 256, 0, stream>>>(Cqkv, vTb);
  k_cast<<<4096, 256, 0, stream>>>(wo, Wo, 1048576);

  k_attn<<<dim3(NH, SEQL / 128, BAT), 256, 0, stream>>>(q_r, k_r, vTb, aout);

  k_gemm_bt<float><<<dim3(DM / 128, MR / 128), 256, 0, stream>>>(aout, Wo, out, DM, DM);
}

// Round 9
// 175.672 us; speedup vs baseline: 1.0809x; 1.0809x over previous
//
#include <hip/hip_runtime.h>
#include <hip/hip_bf16.h>
#include <stdint.h>

// Problem constants
#define DM    2048
#define NH    16
#define NKVH  4
#define HD    128
#define WIN   512
#define SEQL  2048
#define BAT   2
#define MR    (BAT*SEQL)        // 4096 rows
#define NQKV  3072              // 2048 q + 512 k + 512 v
#define QKSCALE 0.08838834764831845f
#define CAP   50.0f
// C1: folded into Q in the fused GEMM epilogue. sv = y * 2*log2e/CAP, y = q.k*QKSCALE
#define C1F (QKSCALE * 2.0f * 1.4426950408889634f / CAP)
#define C2F (-144.26950408889634f)   // -2*CAP*log2e ; p' = 2^(C2F/(2^sv+1))

typedef unsigned short u16;
typedef __attribute__((ext_vector_type(8))) short short8;
typedef __attribute__((ext_vector_type(4))) float f32x4;
typedef __attribute__((ext_vector_type(16))) float f32x16;

__device__ __forceinline__ u16 f2bf(float f) {
  union { float f; uint32_t u; } v; v.f = f;
  uint32_t r = v.u + 0x7FFFu + ((v.u >> 16) & 1u);
  return (u16)(r >> 16);
}
__device__ __forceinline__ float bf2f(u16 h) {
  union { uint32_t u; float f; } v; v.u = ((uint32_t)h) << 16; return v.f;
}
__device__ __forceinline__ void gld16(const void* g, void* l) {
  __builtin_amdgcn_global_load_lds((const __attribute__((address_space(1))) void*)g,
                                   (__attribute__((address_space(3))) void*)l,
                                   16, 0, 0);
}
// p' = exp(CAP*tanh(y/CAP)) / e^CAP = 2^( C2F / (2^sv + 1) ), sv pre-scaled via C1F.
// Real intrinsics (not inline asm) so TRANS hazard wait-states are inserted (R6 fix).
__device__ __forceinline__ float exp_softcap(float sv) {
  float t = __builtin_amdgcn_exp2f(sv);
  float u = __builtin_amdgcn_rcpf(t + 1.0f);
  return __builtin_amdgcn_exp2f(u * C2F);
}

// ---------------- elementwise: fp32 -> bf16 cast ----------------
__global__ void k_cast(const float* __restrict__ src, u16* __restrict__ dst, int n4) {
  int i = blockIdx.x * 256 + threadIdx.x;
  if (i >= n4) return;
  float4 v = ((const float4*)src)[i];
  ushort4 o;
  o.x = f2bf(v.x); o.y = f2bf(v.y); o.z = f2bf(v.z); o.w = f2bf(v.w);
  ((ushort4*)dst)[i] = o;
}

// ---------------- RoPE cos/sin table: [S][64] ----------------
__global__ void k_rope_table(float* __restrict__ c, float* __restrict__ sn) {
  int s = blockIdx.x, i = threadIdx.x;
  float invf = expf(-(float)i * (9.210340371976184f / 64.0f));
  float a = (float)s * invf;
  c[(s << 6) + i]  = cosf(a);
  sn[(s << 6) + i] = sinf(a);
}

// ---------------- fused QKV GEMM: C = A * Wqkv^T with RoPE + scatter epilogue ----
// Hot loop = m97 structure (unchanged, ~880 TF). Epilogue fuses:
//  - q cols (bn<16):  RoPE (pair exchange via LDS bounce with wave wid^1) + C1F
//                     -> q_r[b][h][s][d]
//  - k cols (16..19): RoPE -> k_r[b][kvh][s][d]
//  - v cols (20..23): transpose-write -> vt[b][kvh][d][s] (ushort4 per lane)
// Pair (d, d+64) lives at SAME lane/acc-index in partner wave wid^1 (wr depends
// only on wid>>1, wc only on wid&1) -> exchange needs no index math.
__global__ __launch_bounds__(256, 3) void k_gemm_qkv(const u16* __restrict__ A,
                                                     const u16* __restrict__ Bm,
                                                     u16* __restrict__ qrout,
                                                     u16* __restrict__ krout,
                                                     u16* __restrict__ vtout,
                                                     const float* __restrict__ cosT,
                                                     const float* __restrict__ sinT) {
  __shared__ __align__(16) u16 ldsbuf[2 * 128 * 64];   // 32 KB: A|B staging, epi exch
  u16* ldsA = ldsbuf;
  u16* ldsB = ldsbuf + 128 * 64;
  const int t = threadIdx.x;
  const int K = DM;

  const int nwg  = gridDim.x * gridDim.y;               // 24*32 = 768, %8==0
  const int flat = blockIdx.y * gridDim.x + blockIdx.x;
  const int cpx  = nwg >> 3;
  const int swz  = (flat & 7) * cpx + (flat >> 3);
  const int bn = swz % gridDim.x, bm = swz / gridDim.x;

  const int m0 = bm * 128, n0 = bn * 128;
  const int lane = t & 63, wid = t >> 6;
  const int lr = lane & 15, lk = lane >> 4;
  const int wr = (wid >> 1) * 64, wc = (wid & 1) * 64;
  const int nt = K >> 6;

  const int srow = t >> 3;
  const int scol = (((t & 7) ^ (srow & 7)) << 3);

  f32x4 acc[4][4];
  #pragma unroll
  for (int mi = 0; mi < 4; ++mi)
    #pragma unroll
    for (int ni = 0; ni < 4; ++ni) acc[mi][ni] = f32x4{0.f, 0.f, 0.f, 0.f};

  for (int kt = 0; kt < nt; ++kt) {
    {
      const u16* a0 = A  + (size_t)(m0 + srow) * K + kt * 64 + scol;
      const u16* b0 = Bm + (size_t)(n0 + srow) * K + kt * 64 + scol;
      #pragma unroll
      for (int i = 0; i < 4; ++i) {
        gld16(a0 + (size_t)(i * 32) * K, &ldsA[i * 2048 + t * 8]);
        gld16(b0 + (size_t)(i * 32) * K, &ldsB[i * 2048 + t * 8]);
      }
    }
    __syncthreads();
    #pragma unroll
    for (int ks = 0; ks < 2; ++ks) {
      const int c = ks * 4 + lk;
      short8 af[4], bfv[4];
      #pragma unroll
      for (int mi = 0; mi < 4; ++mi) {
        const int ra = wr + mi * 16 + lr;
        af[mi] = *(const short8*)(ldsA + ra * 64 + ((c ^ (ra & 7)) << 3));
      }
      #pragma unroll
      for (int ni = 0; ni < 4; ++ni) {
        const int rb = wc + ni * 16 + lr;
        bfv[ni] = *(const short8*)(ldsB + rb * 64 + ((c ^ (rb & 7)) << 3));
      }
      #pragma unroll
      for (int mi = 0; mi < 4; ++mi)
        #pragma unroll
        for (int ni = 0; ni < 4; ++ni)
          acc[mi][ni] = __builtin_amdgcn_mfma_f32_16x16x32_bf16(af[mi], bfv[ni], acc[mi][ni], 0, 0, 0);
    }
    if (kt + 1 < nt) __syncthreads();
  }

  // ---- fused epilogue ----
  __syncthreads();                       // protect LDS reuse (laggard waves still read)
  const int bb2 = m0 >> 11;              // batch (128 | 2048, uniform per block)

  if (bn < 20) {
    // RoPE path (q and k): exchange partner-half values through LDS
    float* exch = (float*)ldsbuf;        // [4 wid][32 j][64 lane] f32 = 32 KB
    const bool isq = (bn < 16);
    u16* obase = isq ? (qrout + (size_t)(bb2 * NH + bn) * SEQL * HD)
                     : (krout + (size_t)(bb2 * NKVH + (bn - 16)) * SEQL * HD);
    #pragma unroll
    for (int half = 0; half < 2; ++half) {
      #pragma unroll
      for (int mi2 = 0; mi2 < 2; ++mi2)
        #pragma unroll
        for (int ni = 0; ni < 4; ++ni)
          #pragma unroll
          for (int r = 0; r < 4; ++r)
            exch[(wid * 32 + mi2 * 16 + ni * 4 + r) * 64 + lane] = acc[half * 2 + mi2][ni][r];
      __syncthreads();
      #pragma unroll
      for (int mi2 = 0; mi2 < 2; ++mi2) {
        const int mi = half * 2 + mi2;
        const int rbase = m0 + wr + mi * 16 + lk * 4;
        #pragma unroll
        for (int ni = 0; ni < 4; ++ni) {
          const int d64 = ni * 16 + lr;        // rope index 0..63
          const int d   = wc + d64;            // col within head
          #pragma unroll
          for (int r = 0; r < 4; ++r) {
            const int s = (rbase + r) & (SEQL - 1);
            float x = acc[mi][ni][r];
            float y = exch[((wid ^ 1) * 32 + mi2 * 16 + ni * 4 + r) * 64 + lane];
            float cc = cosT[(s << 6) + d64], ss = sinT[(s << 6) + d64];
            float ov = (wc == 0) ? (x * cc - y * ss) : (x * cc + y * ss);
            if (isq) ov *= C1F;
            obase[(size_t)s * HD + d] = f2bf(ov);
          }
        }
      }
      __syncthreads();
    }
  } else {
    // V path: transposed write vt[b][kvh][d][s]; 4 consecutive s per lane (8B)
    const int kvh = bn - 20;
    u16* vb = vtout + (size_t)(bb2 * NKVH + kvh) * HD * SEQL;
    #pragma unroll
    for (int mi = 0; mi < 4; ++mi) {
      const int s0 = (m0 + wr + mi * 16 + lk * 4) & (SEQL - 1);
      #pragma unroll
      for (int ni = 0; ni < 4; ++ni) {
        const int d = wc + ni * 16 + lr;
        ushort4 w4;
        w4.x = f2bf(acc[mi][ni][0]); w4.y = f2bf(acc[mi][ni][1]);
        w4.z = f2bf(acc[mi][ni][2]); w4.w = f2bf(acc[mi][ni][3]);
        *(ushort4*)(vb + (size_t)d * SEQL + s0) = w4;
      }
    }
  }
}

// ---------------- GEMM: C[M][N] = A[M][K] * B[N][K]^T (AO projection, unchanged) ----
template <typename OutT>
__global__ __launch_bounds__(256, 3) void k_gemm_bt(const u16* __restrict__ A,
                                                    const u16* __restrict__ Bm,
                                                    OutT* __restrict__ C,
                                                    int N, int K) {
  __shared__ __align__(16) u16 ldsA[128 * 64];
  __shared__ __align__(16) u16 ldsB[128 * 64];
  const int t = threadIdx.x;

  const int nwg  = gridDim.x * gridDim.y;
  const int flat = blockIdx.y * gridDim.x + blockIdx.x;
  const int cpx  = nwg >> 3;
  const int swz  = (flat & 7) * cpx + (flat >> 3);
  const int bn = swz % gridDim.x, bm = swz / gridDim.x;

  const int m0 = bm * 128, n0 = bn * 128;
  const int lane = t & 63, wid = t >> 6;
  const int lr = lane & 15, lk = lane >> 4;
  const int wr = (wid >> 1) * 64, wc = (wid & 1) * 64;
  const int nt = K >> 6;

  const int srow = t >> 3;
  const int scol = (((t & 7) ^ (srow & 7)) << 3);

  f32x4 acc[4][4];
  #pragma unroll
  for (int mi = 0; mi < 4; ++mi)
    #pragma unroll
    for (int ni = 0; ni < 4; ++ni) acc[mi][ni] = f32x4{0.f, 0.f, 0.f, 0.f};

  for (int kt = 0; kt < nt; ++kt) {
    {
      const u16* a0 = A  + (size_t)(m0 + srow) * K + kt * 64 + scol;
      const u16* b0 = Bm + (size_t)(n0 + srow) * K + kt * 64 + scol;
      #pragma unroll
      for (int i = 0; i < 4; ++i) {
        gld16(a0 + (size_t)(i * 32) * K, &ldsA[i * 2048 + t * 8]);
        gld16(b0 + (size_t)(i * 32) * K, &ldsB[i * 2048 + t * 8]);
      }
    }
    __syncthreads();
    #pragma unroll
    for (int ks = 0; ks < 2; ++ks) {
      const int c = ks * 4 + lk;
      short8 af[4], bfv[4];
      #pragma unroll
      for (int mi = 0; mi < 4; ++mi) {
        const int ra = wr + mi * 16 + lr;
        af[mi] = *(const short8*)(ldsA + ra * 64 + ((c ^ (ra & 7)) << 3));
      }
      #pragma unroll
      for (int ni = 0; ni < 4; ++ni) {
        const int rb = wc + ni * 16 + lr;
        bfv[ni] = *(const short8*)(ldsB + rb * 64 + ((c ^ (rb & 7)) << 3));
      }
      #pragma unroll
      for (int mi = 0; mi < 4; ++mi)
        #pragma unroll
        for (int ni = 0; ni < 4; ++ni)
          acc[mi][ni] = __builtin_amdgcn_mfma_f32_16x16x32_bf16(af[mi], bfv[ni], acc[mi][ni], 0, 0, 0);
    }
    if (kt + 1 < nt) __syncthreads();
  }

  #pragma unroll
  for (int mi = 0; mi < 4; ++mi) {
    #pragma unroll
    for (int ni = 0; ni < 4; ++ni) {
      const int r0 = m0 + wr + mi * 16 + lk * 4;
      const int c  = n0 + wc + ni * 16 + lr;
      #pragma unroll
      for (int r = 0; r < 4; ++r) {
        float v = acc[mi][ni][r];
        if constexpr (__is_same(OutT, float)) C[(size_t)(r0 + r) * N + c] = v;
        else                                  C[(size_t)(r0 + r) * N + c] = f2bf(v);
      }
    }
  }
}

// ---------------- flash attention (unchanged from R8: 32x32x16, in-reg P) ----------
__global__ __launch_bounds__(256, 2) void k_attn(const u16* __restrict__ qr,
                                                 const u16* __restrict__ kr,
                                                 const u16* __restrict__ vt,
                                                 u16* __restrict__ ao) {
  __shared__ __align__(16) u16 kbuf[2][32 * 128];   // [kv][d], byte bits[6:4]^=row&7
  __shared__ __align__(16) u16 vbuf[2][128 * 32];   // [d][kv], byte bits[5:4]^=(row>>1)&3

  const int t = threadIdx.x;
  const int wid = t >> 6, lane = t & 63;
  const int l31 = lane & 31, lh = lane >> 5;
  const int h = blockIdx.x, bq = blockIdx.y, b = blockIdx.z;
  const int kvh = h >> 2;
  const int Q0 = bq * 128;
  const int q0w = Q0 + wid * 32;
  const u16* qb = qr + (size_t)(b * NH + h) * SEQL * HD;
  const u16* kb = kr + (size_t)(b * NKVH + kvh) * SEQL * HD;
  const u16* vb = vt + (size_t)(b * NKVH + kvh) * HD * SEQL;

  short8 qf[8];
  #pragma unroll
  for (int ks = 0; ks < 8; ++ks)
    qf[ks] = *(const short8*)(qb + (size_t)(q0w + l31) * HD + ks * 16 + lh * 8);

  f32x16 o[4];
  #pragma unroll
  for (int dt = 0; dt < 4; ++dt)
    #pragma unroll
    for (int i = 0; i < 16; ++i) o[dt][i] = 0.f;
  float lsum = 0.f;

  int lo = Q0 - (WIN - 1); if (lo < 0) lo = 0;
  const int ktlo = lo >> 5, kthi = (Q0 + 127) >> 5;

  auto stageK = [&](int bufi, int kv0) {
    #pragma unroll
    for (int i = 0; i < 2; ++i) {
      int c = t + i * 256;
      int bb = c << 4;
      int sb = bb ^ (((bb >> 8) & 7) << 4);
      gld16(kb + (size_t)(kv0 + (sb >> 8)) * HD + ((sb & 255) >> 1),
            &kbuf[bufi][c << 3]);
    }
  };
  auto stageV = [&](int bufi, int kv0) {
    #pragma unroll
    for (int i = 0; i < 2; ++i) {
      int c = t + i * 256;
      int bb = c << 4;
      int sb = bb ^ (((bb >> 7) & 3) << 4);
      gld16(vb + (size_t)(sb >> 6) * SEQL + kv0 + ((sb & 63) >> 1),
            &vbuf[bufi][c << 3]);
    }
  };

  stageK(0, ktlo << 5);
  stageV(0, ktlo << 5);
  __syncthreads();

  for (int kt = ktlo; kt <= kthi; ++kt) {
    const int cur = kt & 1;
    if (kt < kthi) { stageK(cur ^ 1, (kt + 1) << 5); stageV(cur ^ 1, (kt + 1) << 5); }
    const int kv0 = kt << 5;
    if (kv0 + 31 >= q0w - (WIN - 1) && kv0 <= q0w + 31) {
      f32x16 sv;
      #pragma unroll
      for (int i = 0; i < 16; ++i) sv[i] = 0.f;
      const u16* lks = kbuf[cur];
      #pragma unroll
      for (int ks = 0; ks < 8; ++ks) {
        int bo = (l31 * 256 + ks * 32 + lh * 16) ^ ((l31 & 7) << 4);
        short8 kf = *(const short8*)(lks + (bo >> 1));
        sv = __builtin_amdgcn_mfma_f32_32x32x16_bf16(kf, qf[ks], sv, 0, 0, 0);
      }
      float p[16];
      const bool interior = (kv0 + 31 <= q0w) && (kv0 >= q0w + 32 - WIN);
      if (interior) {
        #pragma unroll
        for (int r = 0; r < 16; ++r) p[r] = exp_softcap(sv[r]);
      } else {
        const int qg = q0w + l31;
        #pragma unroll
        for (int r = 0; r < 16; ++r) {
          const int kg = kv0 + (r & 3) + 8 * (r >> 2) + 4 * lh;
          float e = exp_softcap(sv[r]);
          p[r] = (kg <= qg && kg > qg - WIN) ? e : 0.f;
        }
      }
      #pragma unroll
      for (int r = 0; r < 16; ++r) lsum += p[r];

      uint32_t w[8];
      #pragma unroll
      for (int r2 = 0; r2 < 8; ++r2) {
        __hip_bfloat162 u = __float22bfloat162_rn(float2{p[2 * r2], p[2 * r2 + 1]});
        w[r2] = *(uint32_t*)&u;
      }
      uint32_t z0 = lh ? w[0] : w[2], z1 = lh ? w[1] : w[3];
      uint32_t z2 = lh ? w[4] : w[6], z3 = lh ? w[5] : w[7];
      uint32_t x0 = __shfl_xor((int)z0, 32), x1 = __shfl_xor((int)z1, 32);
      uint32_t x2 = __shfl_xor((int)z2, 32), x3 = __shfl_xor((int)z3, 32);
      union U8 { uint32_t u[4]; short8 s; };
      U8 pa0, pa1;
      pa0.u[0] = lh ? x0 : w[0];  pa0.u[1] = lh ? x1 : w[1];
      pa0.u[2] = lh ? w[2] : x0;  pa0.u[3] = lh ? w[3] : x1;
      pa1.u[0] = lh ? x2 : w[4];  pa1.u[1] = lh ? x3 : w[5];
      pa1.u[2] = lh ? w[6] : x2;  pa1.u[3] = lh ? w[7] : x3;

      const u16* lvs = vbuf[cur];
      #pragma unroll
      for (int ks2 = 0; ks2 < 2; ++ks2) {
        const short8 paf = ks2 ? pa1.s : pa0.s;
        #pragma unroll
        for (int dt = 0; dt < 4; ++dt) {
          int row = dt * 32 + l31;
          int bo = (row * 64 + ks2 * 32 + lh * 16) ^ (((row >> 1) & 3) << 4);
          short8 vf = *(const short8*)(lvs + (bo >> 1));
          o[dt] = __builtin_amdgcn_mfma_f32_32x32x16_bf16(paf, vf, o[dt], 0, 0, 0);
        }
      }
    }
    __syncthreads();
  }

  lsum += __shfl_xor(lsum, 32);
  float linv = 1.0f / lsum;
  #pragma unroll
  for (int rr = 0; rr < 4; ++rr) {
    #pragma unroll
    for (int r = 0; r < 4; ++r) {
      const int crow = r + 8 * rr + 4 * lh;
      float inv = __shfl(linv, crow);
      const int srow = q0w + crow;
      u16* op = ao + (size_t)(b * SEQL + srow) * DM + h * HD;
      #pragma unroll
      for (int dt = 0; dt < 4; ++dt)
        op[dt * 32 + l31] = f2bf(o[dt][rr * 4 + r] * inv);
    }
  }
}

extern "C" void kernel_launch(void* const* d_in, const int* in_sizes, int n_in,
                              void* d_out, int out_size, void* d_ws, size_t ws_size,
                              hipStream_t stream) {
  (void)in_sizes; (void)n_in; (void)out_size; (void)ws_size;
  const float* hs = (const float*)d_in[0];
  const float* wq = (const float*)d_in[1];
  const float* wk = (const float*)d_in[2];
  const float* wv = (const float*)d_in[3];
  const float* wo = (const float*)d_in[4];
  float* out = (float*)d_out;

  u16* ws    = (u16*)d_ws;
  u16* A_bf  = ws;                      //  8,388,608  hs bf16 [4096][2048]
  u16* Wqkv  = A_bf + 8388608;          //  6,291,456  packed [3072][2048]
  u16* Wo    = Wqkv + 6291456;          //  4,194,304  [2048][2048]
  u16* q_r   = Wo + 4194304;            //  8,388,608  [b][h][s][128]
  u16* k_r   = q_r + 8388608;           //  2,097,152  [b][kvh][s][128]
  u16* vTb   = k_r + 2097152;           //  2,097,152  [b][kvh][128][s]
  float* cosT = (float*)(vTb + 2097152);
  float* sinT = cosT + 131072;
  u16* aout = A_bf;                     // reuse A_bf after QKV gemm

  k_cast<<<8192, 256, 0, stream>>>(hs, A_bf, 2097152);
  k_cast<<<4096, 256, 0, stream>>>(wq, Wqkv, 1048576);
  k_cast<<<1024, 256, 0, stream>>>(wk, Wqkv + 4194304, 262144);
  k_cast<<<1024, 256, 0, stream>>>(wv, Wqkv + 5242880, 262144);
  k_cast<<<4096, 256, 0, stream>>>(wo, Wo, 1048576);
  k_rope_table<<<2048, 64, 0, stream>>>(cosT, sinT);

  // fused QKV GEMM + RoPE + V-transpose (writes q_r / k_r / vTb directly)
  k_gemm_qkv<<<dim3(NQKV / 128, MR / 128), 256, 0, stream>>>(A_bf, Wqkv, q_r, k_r, vTb,
                                                             cosT, sinT);

  k_attn<<<dim3(NH, SEQL / 128, BAT), 256, 0, stream>>>(q_r, k_r, vTb, aout);

  k_gemm_bt<float><<<dim3(DM / 128, MR / 128), 256, 0, stream>>>(aout, Wo, out, DM, DM);
}

// Round 10
// 174.001 us; speedup vs baseline: 1.0913x; 1.0096x over previous
//
#include <hip/hip_runtime.h>
#include <hip/hip_bf16.h>
#include <stdint.h>

// Problem constants
#define DM    2048
#define NH    16
#define NKVH  4
#define HD    128
#define WIN   512
#define SEQL  2048
#define BAT   2
#define MR    (BAT*SEQL)        // 4096 rows
#define NQKV  3072              // 2048 q + 512 k + 512 v
#define QKSCALE 0.08838834764831845f
#define CAP   50.0f
// C1: folded into Q in the fused GEMM epilogue. sv = y * 2*log2e/CAP, y = q.k*QKSCALE
#define C1F (QKSCALE * 2.0f * 1.4426950408889634f / CAP)
#define C2F (-144.26950408889634f)   // -2*CAP*log2e ; p' = 2^(C2F/(2^sv+1))

typedef unsigned short u16;
typedef __attribute__((ext_vector_type(8))) short short8;
typedef __attribute__((ext_vector_type(4))) float f32x4;
typedef __attribute__((ext_vector_type(16))) float f32x16;

__device__ __forceinline__ u16 f2bf(float f) {
  union { float f; uint32_t u; } v; v.f = f;
  uint32_t r = v.u + 0x7FFFu + ((v.u >> 16) & 1u);
  return (u16)(r >> 16);
}
__device__ __forceinline__ float bf2f(u16 h) {
  union { uint32_t u; float f; } v; v.u = ((uint32_t)h) << 16; return v.f;
}
__device__ __forceinline__ void gld16(const void* g, void* l) {
  __builtin_amdgcn_global_load_lds((const __attribute__((address_space(1))) void*)g,
                                   (__attribute__((address_space(3))) void*)l,
                                   16, 0, 0);
}
// p' = exp(CAP*tanh(y/CAP)) / e^CAP = 2^( C2F / (2^sv + 1) ), sv pre-scaled via C1F.
// Real intrinsics (not inline asm) so TRANS hazard wait-states are inserted (R6 fix).
__device__ __forceinline__ float exp_softcap(float sv) {
  float t = __builtin_amdgcn_exp2f(sv);
  float u = __builtin_amdgcn_rcpf(t + 1.0f);
  return __builtin_amdgcn_exp2f(u * C2F);
}

// ---------------- elementwise: fp32 -> bf16 cast ----------------
__global__ void k_cast(const float* __restrict__ src, u16* __restrict__ dst, int n4) {
  int i = blockIdx.x * 256 + threadIdx.x;
  if (i >= n4) return;
  float4 v = ((const float4*)src)[i];
  ushort4 o;
  o.x = f2bf(v.x); o.y = f2bf(v.y); o.z = f2bf(v.z); o.w = f2bf(v.w);
  ((ushort4*)dst)[i] = o;
}

// ---------------- RoPE cos/sin table: [S][64] ----------------
__global__ void k_rope_table(float* __restrict__ c, float* __restrict__ sn) {
  int s = blockIdx.x, i = threadIdx.x;
  float invf = expf(-(float)i * (9.210340371976184f / 64.0f));
  float a = (float)s * invf;
  c[(s << 6) + i]  = cosf(a);
  sn[(s << 6) + i] = sinf(a);
}

// ---------------- fused QKV GEMM: C = A * Wqkv^T with RoPE + scatter epilogue ----
// (unchanged from R9; 768 blocks = exactly 3/CU, hot loop at structure ceiling)
__global__ __launch_bounds__(256, 3) void k_gemm_qkv(const u16* __restrict__ A,
                                                     const u16* __restrict__ Bm,
                                                     u16* __restrict__ qrout,
                                                     u16* __restrict__ krout,
                                                     u16* __restrict__ vtout,
                                                     const float* __restrict__ cosT,
                                                     const float* __restrict__ sinT) {
  __shared__ __align__(16) u16 ldsbuf[2 * 128 * 64];   // 32 KB: A|B staging, epi exch
  u16* ldsA = ldsbuf;
  u16* ldsB = ldsbuf + 128 * 64;
  const int t = threadIdx.x;
  const int K = DM;

  const int nwg  = gridDim.x * gridDim.y;               // 24*32 = 768, %8==0
  const int flat = blockIdx.y * gridDim.x + blockIdx.x;
  const int cpx  = nwg >> 3;
  const int swz  = (flat & 7) * cpx + (flat >> 3);
  const int bn = swz % gridDim.x, bm = swz / gridDim.x;

  const int m0 = bm * 128, n0 = bn * 128;
  const int lane = t & 63, wid = t >> 6;
  const int lr = lane & 15, lk = lane >> 4;
  const int wr = (wid >> 1) * 64, wc = (wid & 1) * 64;
  const int nt = K >> 6;

  const int srow = t >> 3;
  const int scol = (((t & 7) ^ (srow & 7)) << 3);

  f32x4 acc[4][4];
  #pragma unroll
  for (int mi = 0; mi < 4; ++mi)
    #pragma unroll
    for (int ni = 0; ni < 4; ++ni) acc[mi][ni] = f32x4{0.f, 0.f, 0.f, 0.f};

  for (int kt = 0; kt < nt; ++kt) {
    {
      const u16* a0 = A  + (size_t)(m0 + srow) * K + kt * 64 + scol;
      const u16* b0 = Bm + (size_t)(n0 + srow) * K + kt * 64 + scol;
      #pragma unroll
      for (int i = 0; i < 4; ++i) {
        gld16(a0 + (size_t)(i * 32) * K, &ldsA[i * 2048 + t * 8]);
        gld16(b0 + (size_t)(i * 32) * K, &ldsB[i * 2048 + t * 8]);
      }
    }
    __syncthreads();
    #pragma unroll
    for (int ks = 0; ks < 2; ++ks) {
      const int c = ks * 4 + lk;
      short8 af[4], bfv[4];
      #pragma unroll
      for (int mi = 0; mi < 4; ++mi) {
        const int ra = wr + mi * 16 + lr;
        af[mi] = *(const short8*)(ldsA + ra * 64 + ((c ^ (ra & 7)) << 3));
      }
      #pragma unroll
      for (int ni = 0; ni < 4; ++ni) {
        const int rb = wc + ni * 16 + lr;
        bfv[ni] = *(const short8*)(ldsB + rb * 64 + ((c ^ (rb & 7)) << 3));
      }
      #pragma unroll
      for (int mi = 0; mi < 4; ++mi)
        #pragma unroll
        for (int ni = 0; ni < 4; ++ni)
          acc[mi][ni] = __builtin_amdgcn_mfma_f32_16x16x32_bf16(af[mi], bfv[ni], acc[mi][ni], 0, 0, 0);
    }
    if (kt + 1 < nt) __syncthreads();
  }

  // ---- fused epilogue ----
  __syncthreads();
  const int bb2 = m0 >> 11;

  if (bn < 20) {
    float* exch = (float*)ldsbuf;        // [4 wid][32 j][64 lane] f32 = 32 KB
    const bool isq = (bn < 16);
    u16* obase = isq ? (qrout + (size_t)(bb2 * NH + bn) * SEQL * HD)
                     : (krout + (size_t)(bb2 * NKVH + (bn - 16)) * SEQL * HD);
    #pragma unroll
    for (int half = 0; half < 2; ++half) {
      #pragma unroll
      for (int mi2 = 0; mi2 < 2; ++mi2)
        #pragma unroll
        for (int ni = 0; ni < 4; ++ni)
          #pragma unroll
          for (int r = 0; r < 4; ++r)
            exch[(wid * 32 + mi2 * 16 + ni * 4 + r) * 64 + lane] = acc[half * 2 + mi2][ni][r];
      __syncthreads();
      #pragma unroll
      for (int mi2 = 0; mi2 < 2; ++mi2) {
        const int mi = half * 2 + mi2;
        const int rbase = m0 + wr + mi * 16 + lk * 4;
        #pragma unroll
        for (int ni = 0; ni < 4; ++ni) {
          const int d64 = ni * 16 + lr;
          const int d   = wc + d64;
          #pragma unroll
          for (int r = 0; r < 4; ++r) {
            const int s = (rbase + r) & (SEQL - 1);
            float x = acc[mi][ni][r];
            float y = exch[((wid ^ 1) * 32 + mi2 * 16 + ni * 4 + r) * 64 + lane];
            float cc = cosT[(s << 6) + d64], ss = sinT[(s << 6) + d64];
            float ov = (wc == 0) ? (x * cc - y * ss) : (x * cc + y * ss);
            if (isq) ov *= C1F;
            obase[(size_t)s * HD + d] = f2bf(ov);
          }
        }
      }
      __syncthreads();
    }
  } else {
    const int kvh = bn - 20;
    u16* vb = vtout + (size_t)(bb2 * NKVH + kvh) * HD * SEQL;
    #pragma unroll
    for (int mi = 0; mi < 4; ++mi) {
      const int s0 = (m0 + wr + mi * 16 + lk * 4) & (SEQL - 1);
      #pragma unroll
      for (int ni = 0; ni < 4; ++ni) {
        const int d = wc + ni * 16 + lr;
        ushort4 w4;
        w4.x = f2bf(acc[mi][ni][0]); w4.y = f2bf(acc[mi][ni][1]);
        w4.z = f2bf(acc[mi][ni][2]); w4.w = f2bf(acc[mi][ni][3]);
        *(ushort4*)(vb + (size_t)d * SEQL + s0) = w4;
      }
    }
  }
}

// ---------------- AO GEMM: 512-thread blocks (8 waves, 2Mx4N), 128x128 tile ----
// AO grid is 512 blocks = 2/CU; at 256 threads that's only 8 waves/CU and the
// m97 drain-hiding starves (590 TF vs QKV's 881). 8 waves/block -> 16 waves/CU
// at the SAME tile intensity. Wave quadrant 64x32: 4 A-frags + 2 B-frags,
// 8 MFMA per ks. LDS 32 KB; __launch_bounds__(512,4) = 2 blocks/CU.
__global__ __launch_bounds__(512, 4) void k_gemm_ao(const u16* __restrict__ A,
                                                    const u16* __restrict__ Bm,
                                                    float* __restrict__ C,
                                                    int N, int K) {
  __shared__ __align__(16) u16 ldsA[128 * 64];
  __shared__ __align__(16) u16 ldsB[128 * 64];
  const int t = threadIdx.x;

  const int nwg  = gridDim.x * gridDim.y;               // 16*32 = 512, %8==0
  const int flat = blockIdx.y * gridDim.x + blockIdx.x;
  const int cpx  = nwg >> 3;
  const int swz  = (flat & 7) * cpx + (flat >> 3);
  const int bn = swz % gridDim.x, bm = swz / gridDim.x;

  const int m0 = bm * 128, n0 = bn * 128;
  const int lane = t & 63, wid = t >> 6;                // 8 waves
  const int lr = lane & 15, lk = lane >> 4;
  const int wr = (wid >> 2) * 64, wc = (wid & 3) * 32;  // 2M x 4N
  const int nt = K >> 6;

  // staging: 512 threads cover 1024 chunks (A) + 1024 (B); 2+2 gld16/thread
  const int srow = t >> 3;                              // 0..63
  const int scol = (((t & 7) ^ (srow & 7)) << 3);       // i-invariant (64%8==0)

  f32x4 acc[4][2];
  #pragma unroll
  for (int mi = 0; mi < 4; ++mi)
    #pragma unroll
    for (int ni = 0; ni < 2; ++ni) acc[mi][ni] = f32x4{0.f, 0.f, 0.f, 0.f};

  for (int kt = 0; kt < nt; ++kt) {
    {
      const u16* a0 = A  + (size_t)(m0 + srow) * K + kt * 64 + scol;
      const u16* b0 = Bm + (size_t)(n0 + srow) * K + kt * 64 + scol;
      #pragma unroll
      for (int i = 0; i < 2; ++i) {
        gld16(a0 + (size_t)(i * 64) * K, &ldsA[i * 4096 + t * 8]);
        gld16(b0 + (size_t)(i * 64) * K, &ldsB[i * 4096 + t * 8]);
      }
    }
    __syncthreads();
    #pragma unroll
    for (int ks = 0; ks < 2; ++ks) {
      const int c = ks * 4 + lk;
      short8 af[4], bfv[2];
      #pragma unroll
      for (int mi = 0; mi < 4; ++mi) {
        const int ra = wr + mi * 16 + lr;
        af[mi] = *(const short8*)(ldsA + ra * 64 + ((c ^ (ra & 7)) << 3));
      }
      #pragma unroll
      for (int ni = 0; ni < 2; ++ni) {
        const int rb = wc + ni * 16 + lr;
        bfv[ni] = *(const short8*)(ldsB + rb * 64 + ((c ^ (rb & 7)) << 3));
      }
      #pragma unroll
      for (int mi = 0; mi < 4; ++mi)
        #pragma unroll
        for (int ni = 0; ni < 2; ++ni)
          acc[mi][ni] = __builtin_amdgcn_mfma_f32_16x16x32_bf16(af[mi], bfv[ni], acc[mi][ni], 0, 0, 0);
    }
    if (kt + 1 < nt) __syncthreads();
  }

  #pragma unroll
  for (int mi = 0; mi < 4; ++mi) {
    #pragma unroll
    for (int ni = 0; ni < 2; ++ni) {
      const int r0 = m0 + wr + mi * 16 + lk * 4;
      const int c  = n0 + wc + ni * 16 + lr;
      #pragma unroll
      for (int r = 0; r < 4; ++r)
        C[(size_t)(r0 + r) * N + c] = acc[mi][ni][r];
    }
  }
}

// ---------------- flash attention (unchanged from R8: 32x32x16, in-reg P) ----------
__global__ __launch_bounds__(256, 2) void k_attn(const u16* __restrict__ qr,
                                                 const u16* __restrict__ kr,
                                                 const u16* __restrict__ vt,
                                                 u16* __restrict__ ao) {
  __shared__ __align__(16) u16 kbuf[2][32 * 128];   // [kv][d], byte bits[6:4]^=row&7
  __shared__ __align__(16) u16 vbuf[2][128 * 32];   // [d][kv], byte bits[5:4]^=(row>>1)&3

  const int t = threadIdx.x;
  const int wid = t >> 6, lane = t & 63;
  const int l31 = lane & 31, lh = lane >> 5;
  const int h = blockIdx.x, bq = blockIdx.y, b = blockIdx.z;
  const int kvh = h >> 2;
  const int Q0 = bq * 128;
  const int q0w = Q0 + wid * 32;
  const u16* qb = qr + (size_t)(b * NH + h) * SEQL * HD;
  const u16* kb = kr + (size_t)(b * NKVH + kvh) * SEQL * HD;
  const u16* vb = vt + (size_t)(b * NKVH + kvh) * HD * SEQL;

  short8 qf[8];
  #pragma unroll
  for (int ks = 0; ks < 8; ++ks)
    qf[ks] = *(const short8*)(qb + (size_t)(q0w + l31) * HD + ks * 16 + lh * 8);

  f32x16 o[4];
  #pragma unroll
  for (int dt = 0; dt < 4; ++dt)
    #pragma unroll
    for (int i = 0; i < 16; ++i) o[dt][i] = 0.f;
  float lsum = 0.f;

  int lo = Q0 - (WIN - 1); if (lo < 0) lo = 0;
  const int ktlo = lo >> 5, kthi = (Q0 + 127) >> 5;

  auto stageK = [&](int bufi, int kv0) {
    #pragma unroll
    for (int i = 0; i < 2; ++i) {
      int c = t + i * 256;
      int bb = c << 4;
      int sb = bb ^ (((bb >> 8) & 7) << 4);
      gld16(kb + (size_t)(kv0 + (sb >> 8)) * HD + ((sb & 255) >> 1),
            &kbuf[bufi][c << 3]);
    }
  };
  auto stageV = [&](int bufi, int kv0) {
    #pragma unroll
    for (int i = 0; i < 2; ++i) {
      int c = t + i * 256;
      int bb = c << 4;
      int sb = bb ^ (((bb >> 7) & 3) << 4);
      gld16(vb + (size_t)(sb >> 6) * SEQL + kv0 + ((sb & 63) >> 1),
            &vbuf[bufi][c << 3]);
    }
  };

  stageK(0, ktlo << 5);
  stageV(0, ktlo << 5);
  __syncthreads();

  for (int kt = ktlo; kt <= kthi; ++kt) {
    const int cur = kt & 1;
    if (kt < kthi) { stageK(cur ^ 1, (kt + 1) << 5); stageV(cur ^ 1, (kt + 1) << 5); }
    const int kv0 = kt << 5;
    if (kv0 + 31 >= q0w - (WIN - 1) && kv0 <= q0w + 31) {
      f32x16 sv;
      #pragma unroll
      for (int i = 0; i < 16; ++i) sv[i] = 0.f;
      const u16* lks = kbuf[cur];
      #pragma unroll
      for (int ks = 0; ks < 8; ++ks) {
        int bo = (l31 * 256 + ks * 32 + lh * 16) ^ ((l31 & 7) << 4);
        short8 kf = *(const short8*)(lks + (bo >> 1));
        sv = __builtin_amdgcn_mfma_f32_32x32x16_bf16(kf, qf[ks], sv, 0, 0, 0);
      }
      float p[16];
      const bool interior = (kv0 + 31 <= q0w) && (kv0 >= q0w + 32 - WIN);
      if (interior) {
        #pragma unroll
        for (int r = 0; r < 16; ++r) p[r] = exp_softcap(sv[r]);
      } else {
        const int qg = q0w + l31;
        #pragma unroll
        for (int r = 0; r < 16; ++r) {
          const int kg = kv0 + (r & 3) + 8 * (r >> 2) + 4 * lh;
          float e = exp_softcap(sv[r]);
          p[r] = (kg <= qg && kg > qg - WIN) ? e : 0.f;
        }
      }
      #pragma unroll
      for (int r = 0; r < 16; ++r) lsum += p[r];

      uint32_t w[8];
      #pragma unroll
      for (int r2 = 0; r2 < 8; ++r2) {
        __hip_bfloat162 u = __float22bfloat162_rn(float2{p[2 * r2], p[2 * r2 + 1]});
        w[r2] = *(uint32_t*)&u;
      }
      uint32_t z0 = lh ? w[0] : w[2], z1 = lh ? w[1] : w[3];
      uint32_t z2 = lh ? w[4] : w[6], z3 = lh ? w[5] : w[7];
      uint32_t x0 = __shfl_xor((int)z0, 32), x1 = __shfl_xor((int)z1, 32);
      uint32_t x2 = __shfl_xor((int)z2, 32), x3 = __shfl_xor((int)z3, 32);
      union U8 { uint32_t u[4]; short8 s; };
      U8 pa0, pa1;
      pa0.u[0] = lh ? x0 : w[0];  pa0.u[1] = lh ? x1 : w[1];
      pa0.u[2] = lh ? w[2] : x0;  pa0.u[3] = lh ? w[3] : x1;
      pa1.u[0] = lh ? x2 : w[4];  pa1.u[1] = lh ? x3 : w[5];
      pa1.u[2] = lh ? w[6] : x2;  pa1.u[3] = lh ? w[7] : x3;

      const u16* lvs = vbuf[cur];
      #pragma unroll
      for (int ks2 = 0; ks2 < 2; ++ks2) {
        const short8 paf = ks2 ? pa1.s : pa0.s;
        #pragma unroll
        for (int dt = 0; dt < 4; ++dt) {
          int row = dt * 32 + l31;
          int bo = (row * 64 + ks2 * 32 + lh * 16) ^ (((row >> 1) & 3) << 4);
          short8 vf = *(const short8*)(lvs + (bo >> 1));
          o[dt] = __builtin_amdgcn_mfma_f32_32x32x16_bf16(paf, vf, o[dt], 0, 0, 0);
        }
      }
    }
    __syncthreads();
  }

  lsum += __shfl_xor(lsum, 32);
  float linv = 1.0f / lsum;
  #pragma unroll
  for (int rr = 0; rr < 4; ++rr) {
    #pragma unroll
    for (int r = 0; r < 4; ++r) {
      const int crow = r + 8 * rr + 4 * lh;
      float inv = __shfl(linv, crow);
      const int srow = q0w + crow;
      u16* op = ao + (size_t)(b * SEQL + srow) * DM + h * HD;
      #pragma unroll
      for (int dt = 0; dt < 4; ++dt)
        op[dt * 32 + l31] = f2bf(o[dt][rr * 4 + r] * inv);
    }
  }
}

extern "C" void kernel_launch(void* const* d_in, const int* in_sizes, int n_in,
                              void* d_out, int out_size, void* d_ws, size_t ws_size,
                              hipStream_t stream) {
  (void)in_sizes; (void)n_in; (void)out_size; (void)ws_size;
  const float* hs = (const float*)d_in[0];
  const float* wq = (const float*)d_in[1];
  const float* wk = (const float*)d_in[2];
  const float* wv = (const float*)d_in[3];
  const float* wo = (const float*)d_in[4];
  float* out = (float*)d_out;

  u16* ws    = (u16*)d_ws;
  u16* A_bf  = ws;                      //  8,388,608  hs bf16 [4096][2048]
  u16* Wqkv  = A_bf + 8388608;          //  6,291,456  packed [3072][2048]
  u16* Wo    = Wqkv + 6291456;          //  4,194,304  [2048][2048]
  u16* q_r   = Wo + 4194304;            //  8,388,608  [b][h][s][128]
  u16* k_r   = q_r + 8388608;           //  2,097,152  [b][kvh][s][128]
  u16* vTb   = k_r + 2097152;           //  2,097,152  [b][kvh][128][s]
  float* cosT = (float*)(vTb + 2097152);
  float* sinT = cosT + 131072;
  u16* aout = A_bf;                     // reuse A_bf after QKV gemm

  k_cast<<<8192, 256, 0, stream>>>(hs, A_bf, 2097152);
  k_cast<<<4096, 256, 0, stream>>>(wq, Wqkv, 1048576);
  k_cast<<<1024, 256, 0, stream>>>(wk, Wqkv + 4194304, 262144);
  k_cast<<<1024, 256, 0, stream>>>(wv, Wqkv + 5242880, 262144);
  k_cast<<<4096, 256, 0, stream>>>(wo, Wo, 1048576);
  k_rope_table<<<2048, 64, 0, stream>>>(cosT, sinT);

  // fused QKV GEMM + RoPE + V-transpose (writes q_r / k_r / vTb directly)
  k_gemm_qkv<<<dim3(NQKV / 128, MR / 128), 256, 0, stream>>>(A_bf, Wqkv, q_r, k_r, vTb,
                                                             cosT, sinT);

  k_attn<<<dim3(NH, SEQL / 128, BAT), 256, 0, stream>>>(q_r, k_r, vTb, aout);

  // AO projection: 512-thread blocks for 16 waves/CU at 2 blocks/CU
  k_gemm_ao<<<dim3(DM / 128, MR / 128), 512, 0, stream>>>(aout, Wo, out, DM, DM);
}

// Round 11
// 164.002 us; speedup vs baseline: 1.1578x; 1.0610x over previous
//
#include <hip/hip_runtime.h>
#include <hip/hip_bf16.h>
#include <stdint.h>

// Problem constants
#define DM    2048
#define NH    16
#define NKVH  4
#define HD    128
#define WIN   512
#define SEQL  2048
#define BAT   2
#define MR    (BAT*SEQL)        // 4096 rows
#define NQKV  3072              // 2048 q + 512 k + 512 v
#define QKSCALE 0.08838834764831845f
#define CAP   50.0f
// C1: folded into Q in the fused GEMM epilogue. sv = y * 2*log2e/CAP, y = q.k*QKSCALE
#define C1F (QKSCALE * 2.0f * 1.4426950408889634f / CAP)
#define C2F (-144.26950408889634f)   // -2*CAP*log2e ; p' = 2^(C2F/(2^sv+1))

typedef unsigned short u16;
typedef __attribute__((ext_vector_type(8))) short short8;
typedef __attribute__((ext_vector_type(4))) float f32x4;
typedef __attribute__((ext_vector_type(16))) float f32x16;

__device__ __forceinline__ u16 f2bf(float f) {
  union { float f; uint32_t u; } v; v.f = f;
  uint32_t r = v.u + 0x7FFFu + ((v.u >> 16) & 1u);
  return (u16)(r >> 16);
}
__device__ __forceinline__ float bf2f(u16 h) {
  union { uint32_t u; float f; } v; v.u = ((uint32_t)h) << 16; return v.f;
}
__device__ __forceinline__ void gld16(const void* g, void* l) {
  __builtin_amdgcn_global_load_lds((const __attribute__((address_space(1))) void*)g,
                                   (__attribute__((address_space(3))) void*)l,
                                   16, 0, 0);
}
// p' = exp(CAP*tanh(y/CAP)) / e^CAP = 2^( C2F / (2^sv + 1) ), sv pre-scaled via C1F.
// Real intrinsics (not inline asm) so TRANS hazard wait-states are inserted (R6 fix).
__device__ __forceinline__ float exp_softcap(float sv) {
  float t = __builtin_amdgcn_exp2f(sv);
  float u = __builtin_amdgcn_rcpf(t + 1.0f);
  return __builtin_amdgcn_exp2f(u * C2F);
}

// ---------------- fused prep: all fp32->bf16 casts + RoPE table, one launch ----------
// Segment boundaries are block-aligned (each /256): hs 8192 blocks, wq 4096,
// wk 1024, wv 1024, wo 4096 (= 18432 cast blocks), then 512 rope-table blocks.
__global__ void k_prep(const float* __restrict__ hs, const float* __restrict__ wq,
                       const float* __restrict__ wk, const float* __restrict__ wv,
                       const float* __restrict__ wo,
                       u16* __restrict__ A_bf, u16* __restrict__ Wqkv,
                       u16* __restrict__ Wo,
                       float* __restrict__ cosT, float* __restrict__ sinT) {
  const int bid = blockIdx.x;
  if (bid < 18432) {
    const int g = bid * 256 + threadIdx.x;     // float4 index
    const float* src; u16* dst; int off;
    if (g < 2097152)      { src = hs; dst = A_bf;           off = 0; }
    else if (g < 3145728) { src = wq; dst = Wqkv;           off = 2097152; }
    else if (g < 3407872) { src = wk; dst = Wqkv + 4194304; off = 3145728; }
    else if (g < 3670016) { src = wv; dst = Wqkv + 5242880; off = 3407872; }
    else                  { src = wo; dst = Wo;             off = 3670016; }
    const int li = g - off;
    float4 v = ((const float4*)src)[li];
    ushort4 o;
    o.x = f2bf(v.x); o.y = f2bf(v.y); o.z = f2bf(v.z); o.w = f2bf(v.w);
    ((ushort4*)dst)[li] = o;
  } else {
    const int rt = (bid - 18432) * 256 + threadIdx.x;  // 0..131071
    const int s = rt >> 6, i = rt & 63;
    float invf = expf(-(float)i * (9.210340371976184f / 64.0f));
    float a = (float)s * invf;
    cosT[rt] = cosf(a);
    sinT[rt] = sinf(a);
  }
}

// ---------------- fused QKV GEMM: C = A * Wqkv^T with IN-REGISTER RoPE epilogue ----
// Wave layout 4M x 1N (wr = wid*32, full 128-col span per wave): the RoPE pair
// (d, d+64) is acc[mi][ni] / acc[mi][ni+4] in the SAME thread -> epilogue needs
// no LDS exchange and no barriers (was ~11us). Hot loop: af[2] + bfv[8] per ks.
__global__ __launch_bounds__(256, 3) void k_gemm_qkv(const u16* __restrict__ A,
                                                     const u16* __restrict__ Bm,
                                                     u16* __restrict__ qrout,
                                                     u16* __restrict__ krout,
                                                     u16* __restrict__ vtout,
                                                     const float* __restrict__ cosT,
                                                     const float* __restrict__ sinT) {
  __shared__ __align__(16) u16 ldsA[128 * 64];
  __shared__ __align__(16) u16 ldsB[128 * 64];
  const int t = threadIdx.x;
  const int K = DM;

  const int nwg  = gridDim.x * gridDim.y;               // 24*32 = 768, %8==0
  const int flat = blockIdx.y * gridDim.x + blockIdx.x;
  const int cpx  = nwg >> 3;
  const int swz  = (flat & 7) * cpx + (flat >> 3);
  const int bn = swz % gridDim.x, bm = swz / gridDim.x;

  const int m0 = bm * 128, n0 = bn * 128;
  const int lane = t & 63, wid = t >> 6;
  const int lr = lane & 15, lk = lane >> 4;
  const int wr = wid * 32;                              // 4M x 1N
  const int nt = K >> 6;
  (void)n0;

  const int srow = t >> 3;
  const int scol = (((t & 7) ^ (srow & 7)) << 3);

  f32x4 acc[2][8];
  #pragma unroll
  for (int mi = 0; mi < 2; ++mi)
    #pragma unroll
    for (int ni = 0; ni < 8; ++ni) acc[mi][ni] = f32x4{0.f, 0.f, 0.f, 0.f};

  for (int kt = 0; kt < nt; ++kt) {
    {
      const u16* a0 = A  + (size_t)(m0 + srow) * K + kt * 64 + scol;
      const u16* b0 = Bm + (size_t)(bn * 128 + srow) * K + kt * 64 + scol;
      #pragma unroll
      for (int i = 0; i < 4; ++i) {
        gld16(a0 + (size_t)(i * 32) * K, &ldsA[i * 2048 + t * 8]);
        gld16(b0 + (size_t)(i * 32) * K, &ldsB[i * 2048 + t * 8]);
      }
    }
    __syncthreads();
    #pragma unroll
    for (int ks = 0; ks < 2; ++ks) {
      const int c = ks * 4 + lk;
      short8 af[2], bfv[8];
      #pragma unroll
      for (int mi = 0; mi < 2; ++mi) {
        const int ra = wr + mi * 16 + lr;
        af[mi] = *(const short8*)(ldsA + ra * 64 + ((c ^ (ra & 7)) << 3));
      }
      #pragma unroll
      for (int ni = 0; ni < 8; ++ni) {
        const int rb = ni * 16 + lr;
        bfv[ni] = *(const short8*)(ldsB + rb * 64 + ((c ^ (rb & 7)) << 3));
      }
      #pragma unroll
      for (int mi = 0; mi < 2; ++mi)
        #pragma unroll
        for (int ni = 0; ni < 8; ++ni)
          acc[mi][ni] = __builtin_amdgcn_mfma_f32_16x16x32_bf16(af[mi], bfv[ni], acc[mi][ni], 0, 0, 0);
    }
    if (kt + 1 < nt) __syncthreads();
  }

  // ---- fused epilogue (no barriers, no LDS) ----
  const int bb2 = m0 >> 11;

  if (bn < 20) {
    const bool isq = (bn < 16);
    u16* obase = isq ? (qrout + (size_t)(bb2 * NH + bn) * SEQL * HD)
                     : (krout + (size_t)(bb2 * NKVH + (bn - 16)) * SEQL * HD);
    #pragma unroll
    for (int mi = 0; mi < 2; ++mi) {
      const int rbase = m0 + wr + mi * 16 + lk * 4;
      #pragma unroll
      for (int ni = 0; ni < 4; ++ni) {
        const int d64 = ni * 16 + lr;
        #pragma unroll
        for (int r = 0; r < 4; ++r) {
          const int s = (rbase + r) & (SEQL - 1);
          float x = acc[mi][ni][r];          // d = d64
          float y = acc[mi][ni + 4][r];      // d = d64 + 64
          float cc = cosT[(s << 6) + d64], ss = sinT[(s << 6) + d64];
          float o0 = x * cc - y * ss;
          float o1 = y * cc + x * ss;
          if (isq) { o0 *= C1F; o1 *= C1F; }
          obase[(size_t)s * HD + d64]      = f2bf(o0);
          obase[(size_t)s * HD + d64 + 64] = f2bf(o1);
        }
      }
    }
  } else {
    const int kvh = bn - 20;
    u16* vb = vtout + (size_t)(bb2 * NKVH + kvh) * HD * SEQL;
    #pragma unroll
    for (int mi = 0; mi < 2; ++mi) {
      const int s0 = (m0 + wr + mi * 16 + lk * 4) & (SEQL - 1);
      #pragma unroll
      for (int ni = 0; ni < 8; ++ni) {
        const int d = ni * 16 + lr;
        ushort4 w4;
        w4.x = f2bf(acc[mi][ni][0]); w4.y = f2bf(acc[mi][ni][1]);
        w4.z = f2bf(acc[mi][ni][2]); w4.w = f2bf(acc[mi][ni][3]);
        *(ushort4*)(vb + (size_t)d * SEQL + s0) = w4;
      }
    }
  }
}

// ---------------- AO GEMM: 128x64 tile -> 1024 blocks = 4 barrier domains/CU ----
// R10 lesson: drain-hiding scales with INDEPENDENT blocks per CU, not waves per
// block (512-thread/2-block was neutral). 24KB LDS, launch_bounds(256,4):
// 4 blocks x 4 waves = 16 waves/CU in 4 independent barrier domains.
__global__ __launch_bounds__(256, 4) void k_gemm_ao(const u16* __restrict__ A,
                                                    const u16* __restrict__ Bm,
                                                    float* __restrict__ C,
                                                    int N, int K) {
  __shared__ __align__(16) u16 ldsA[128 * 64];   // 16 KB
  __shared__ __align__(16) u16 ldsB[64 * 64];    //  8 KB
  const int t = threadIdx.x;

  const int nwg  = gridDim.x * gridDim.y;        // 32*32 = 1024, %8==0
  const int flat = blockIdx.y * gridDim.x + blockIdx.x;
  const int cpx  = nwg >> 3;
  const int swz  = (flat & 7) * cpx + (flat >> 3);
  const int bn = swz % gridDim.x, bm = swz / gridDim.x;

  const int m0 = bm * 128, n0 = bn * 64;
  const int lane = t & 63, wid = t >> 6;
  const int lr = lane & 15, lk = lane >> 4;
  const int wr = (wid >> 1) * 64, wc = (wid & 1) * 32;  // 2M x 2N, 64x32/wave
  const int nt = K >> 6;

  const int srow = t >> 3;
  const int scol = (((t & 7) ^ (srow & 7)) << 3);

  f32x4 acc[4][2];
  #pragma unroll
  for (int mi = 0; mi < 4; ++mi)
    #pragma unroll
    for (int ni = 0; ni < 2; ++ni) acc[mi][ni] = f32x4{0.f, 0.f, 0.f, 0.f};

  for (int kt = 0; kt < nt; ++kt) {
    {
      const u16* a0 = A  + (size_t)(m0 + srow) * K + kt * 64 + scol;
      const u16* b0 = Bm + (size_t)(n0 + srow) * K + kt * 64 + scol;
      #pragma unroll
      for (int i = 0; i < 4; ++i)
        gld16(a0 + (size_t)(i * 32) * K, &ldsA[i * 2048 + t * 8]);
      #pragma unroll
      for (int i = 0; i < 2; ++i)
        gld16(b0 + (size_t)(i * 32) * K, &ldsB[i * 2048 + t * 8]);
    }
    __syncthreads();
    #pragma unroll
    for (int ks = 0; ks < 2; ++ks) {
      const int c = ks * 4 + lk;
      short8 af[4], bfv[2];
      #pragma unroll
      for (int mi = 0; mi < 4; ++mi) {
        const int ra = wr + mi * 16 + lr;
        af[mi] = *(const short8*)(ldsA + ra * 64 + ((c ^ (ra & 7)) << 3));
      }
      #pragma unroll
      for (int ni = 0; ni < 2; ++ni) {
        const int rb = wc + ni * 16 + lr;
        bfv[ni] = *(const short8*)(ldsB + rb * 64 + ((c ^ (rb & 7)) << 3));
      }
      #pragma unroll
      for (int mi = 0; mi < 4; ++mi)
        #pragma unroll
        for (int ni = 0; ni < 2; ++ni)
          acc[mi][ni] = __builtin_amdgcn_mfma_f32_16x16x32_bf16(af[mi], bfv[ni], acc[mi][ni], 0, 0, 0);
    }
    if (kt + 1 < nt) __syncthreads();
  }

  #pragma unroll
  for (int mi = 0; mi < 4; ++mi) {
    #pragma unroll
    for (int ni = 0; ni < 2; ++ni) {
      const int r0 = m0 + wr + mi * 16 + lk * 4;
      const int c  = n0 + wc + ni * 16 + lr;
      #pragma unroll
      for (int r = 0; r < 4; ++r)
        C[(size_t)(r0 + r) * N + c] = acc[mi][ni][r];
    }
  }
}

// ---------------- flash attention (unchanged: 32x32x16, in-reg P) ----------
__global__ __launch_bounds__(256, 2) void k_attn(const u16* __restrict__ qr,
                                                 const u16* __restrict__ kr,
                                                 const u16* __restrict__ vt,
                                                 u16* __restrict__ ao) {
  __shared__ __align__(16) u16 kbuf[2][32 * 128];   // [kv][d], byte bits[6:4]^=row&7
  __shared__ __align__(16) u16 vbuf[2][128 * 32];   // [d][kv], byte bits[5:4]^=(row>>1)&3

  const int t = threadIdx.x;
  const int wid = t >> 6, lane = t & 63;
  const int l31 = lane & 31, lh = lane >> 5;
  const int h = blockIdx.x, bq = blockIdx.y, b = blockIdx.z;
  const int kvh = h >> 2;
  const int Q0 = bq * 128;
  const int q0w = Q0 + wid * 32;
  const u16* qb = qr + (size_t)(b * NH + h) * SEQL * HD;
  const u16* kb = kr + (size_t)(b * NKVH + kvh) * SEQL * HD;
  const u16* vb = vt + (size_t)(b * NKVH + kvh) * HD * SEQL;

  short8 qf[8];
  #pragma unroll
  for (int ks = 0; ks < 8; ++ks)
    qf[ks] = *(const short8*)(qb + (size_t)(q0w + l31) * HD + ks * 16 + lh * 8);

  f32x16 o[4];
  #pragma unroll
  for (int dt = 0; dt < 4; ++dt)
    #pragma unroll
    for (int i = 0; i < 16; ++i) o[dt][i] = 0.f;
  float lsum = 0.f;

  int lo = Q0 - (WIN - 1); if (lo < 0) lo = 0;
  const int ktlo = lo >> 5, kthi = (Q0 + 127) >> 5;

  auto stageK = [&](int bufi, int kv0) {
    #pragma unroll
    for (int i = 0; i < 2; ++i) {
      int c = t + i * 256;
      int bb = c << 4;
      int sb = bb ^ (((bb >> 8) & 7) << 4);
      gld16(kb + (size_t)(kv0 + (sb >> 8)) * HD + ((sb & 255) >> 1),
            &kbuf[bufi][c << 3]);
    }
  };
  auto stageV = [&](int bufi, int kv0) {
    #pragma unroll
    for (int i = 0; i < 2; ++i) {
      int c = t + i * 256;
      int bb = c << 4;
      int sb = bb ^ (((bb >> 7) & 3) << 4);
      gld16(vb + (size_t)(sb >> 6) * SEQL + kv0 + ((sb & 63) >> 1),
            &vbuf[bufi][c << 3]);
    }
  };

  stageK(0, ktlo << 5);
  stageV(0, ktlo << 5);
  __syncthreads();

  for (int kt = ktlo; kt <= kthi; ++kt) {
    const int cur = kt & 1;
    if (kt < kthi) { stageK(cur ^ 1, (kt + 1) << 5); stageV(cur ^ 1, (kt + 1) << 5); }
    const int kv0 = kt << 5;
    if (kv0 + 31 >= q0w - (WIN - 1) && kv0 <= q0w + 31) {
      f32x16 sv;
      #pragma unroll
      for (int i = 0; i < 16; ++i) sv[i] = 0.f;
      const u16* lks = kbuf[cur];
      #pragma unroll
      for (int ks = 0; ks < 8; ++ks) {
        int bo = (l31 * 256 + ks * 32 + lh * 16) ^ ((l31 & 7) << 4);
        short8 kf = *(const short8*)(lks + (bo >> 1));
        sv = __builtin_amdgcn_mfma_f32_32x32x16_bf16(kf, qf[ks], sv, 0, 0, 0);
      }
      float p[16];
      const bool interior = (kv0 + 31 <= q0w) && (kv0 >= q0w + 32 - WIN);
      if (interior) {
        #pragma unroll
        for (int r = 0; r < 16; ++r) p[r] = exp_softcap(sv[r]);
      } else {
        const int qg = q0w + l31;
        #pragma unroll
        for (int r = 0; r < 16; ++r) {
          const int kg = kv0 + (r & 3) + 8 * (r >> 2) + 4 * lh;
          float e = exp_softcap(sv[r]);
          p[r] = (kg <= qg && kg > qg - WIN) ? e : 0.f;
        }
      }
      #pragma unroll
      for (int r = 0; r < 16; ++r) lsum += p[r];

      uint32_t w[8];
      #pragma unroll
      for (int r2 = 0; r2 < 8; ++r2) {
        __hip_bfloat162 u = __float22bfloat162_rn(float2{p[2 * r2], p[2 * r2 + 1]});
        w[r2] = *(uint32_t*)&u;
      }
      uint32_t z0 = lh ? w[0] : w[2], z1 = lh ? w[1] : w[3];
      uint32_t z2 = lh ? w[4] : w[6], z3 = lh ? w[5] : w[7];
      uint32_t x0 = __shfl_xor((int)z0, 32), x1 = __shfl_xor((int)z1, 32);
      uint32_t x2 = __shfl_xor((int)z2, 32), x3 = __shfl_xor((int)z3, 32);
      union U8 { uint32_t u[4]; short8 s; };
      U8 pa0, pa1;
      pa0.u[0] = lh ? x0 : w[0];  pa0.u[1] = lh ? x1 : w[1];
      pa0.u[2] = lh ? w[2] : x0;  pa0.u[3] = lh ? w[3] : x1;
      pa1.u[0] = lh ? x2 : w[4];  pa1.u[1] = lh ? x3 : w[5];
      pa1.u[2] = lh ? w[6] : x2;  pa1.u[3] = lh ? w[7] : x3;

      const u16* lvs = vbuf[cur];
      #pragma unroll
      for (int ks2 = 0; ks2 < 2; ++ks2) {
        const short8 paf = ks2 ? pa1.s : pa0.s;
        #pragma unroll
        for (int dt = 0; dt < 4; ++dt) {
          int row = dt * 32 + l31;
          int bo = (row * 64 + ks2 * 32 + lh * 16) ^ (((row >> 1) & 3) << 4);
          short8 vf = *(const short8*)(lvs + (bo >> 1));
          o[dt] = __builtin_amdgcn_mfma_f32_32x32x16_bf16(paf, vf, o[dt], 0, 0, 0);
        }
      }
    }
    __syncthreads();
  }

  lsum += __shfl_xor(lsum, 32);
  float linv = 1.0f / lsum;
  #pragma unroll
  for (int rr = 0; rr < 4; ++rr) {
    #pragma unroll
    for (int r = 0; r < 4; ++r) {
      const int crow = r + 8 * rr + 4 * lh;
      float inv = __shfl(linv, crow);
      const int srow = q0w + crow;
      u16* op = ao + (size_t)(b * SEQL + srow) * DM + h * HD;
      #pragma unroll
      for (int dt = 0; dt < 4; ++dt)
        op[dt * 32 + l31] = f2bf(o[dt][rr * 4 + r] * inv);
    }
  }
}

extern "C" void kernel_launch(void* const* d_in, const int* in_sizes, int n_in,
                              void* d_out, int out_size, void* d_ws, size_t ws_size,
                              hipStream_t stream) {
  (void)in_sizes; (void)n_in; (void)out_size; (void)ws_size;
  const float* hs = (const float*)d_in[0];
  const float* wq = (const float*)d_in[1];
  const float* wk = (const float*)d_in[2];
  const float* wv = (const float*)d_in[3];
  const float* wo = (const float*)d_in[4];
  float* out = (float*)d_out;

  u16* ws    = (u16*)d_ws;
  u16* A_bf  = ws;                      //  8,388,608  hs bf16 [4096][2048]
  u16* Wqkv  = A_bf + 8388608;          //  6,291,456  packed [3072][2048]
  u16* Wo    = Wqkv + 6291456;          //  4,194,304  [2048][2048]
  u16* q_r   = Wo + 4194304;            //  8,388,608  [b][h][s][128]
  u16* k_r   = q_r + 8388608;           //  2,097,152  [b][kvh][s][128]
  u16* vTb   = k_r + 2097152;           //  2,097,152  [b][kvh][128][s]
  float* cosT = (float*)(vTb + 2097152);
  float* sinT = cosT + 131072;
  u16* aout = A_bf;                     // reuse A_bf after QKV gemm

  // one fused prep launch: 5 casts + rope table
  k_prep<<<18944, 256, 0, stream>>>(hs, wq, wk, wv, wo, A_bf, Wqkv, Wo, cosT, sinT);

  // fused QKV GEMM + in-register RoPE + V-transpose
  k_gemm_qkv<<<dim3(NQKV / 128, MR / 128), 256, 0, stream>>>(A_bf, Wqkv, q_r, k_r, vTb,
                                                             cosT, sinT);

  k_attn<<<dim3(NH, SEQL / 128, BAT), 256, 0, stream>>>(q_r, k_r, vTb, aout);

  // AO projection: 128x64 tiles -> 1024 blocks = 4 barrier domains/CU
  k_gemm_ao<<<dim3(DM / 64, MR / 128), 256, 0, stream>>>(aout, Wo, out, DM, DM);
}